// Round 9
// baseline (26.611 us; speedup 1.0000x reference)
//
#include <hip/hip_runtime.h>
#include <hip/hip_cooperative_groups.h>
#include <math.h>

#define B_ 32768
#define E_ 256
#define S_ 1024
#define EPS_COS 1e-8f
#define EPS_NORM 1e-12f

typedef float fx4 __attribute__((ext_vector_type(4)));

namespace cg = cooperative_groups;

// =================== fused cooperative kernel (v3) =========================
// Identical to v2 except: plain (cache-allocating) stores instead of
// nontemporal — the 32 MB output stream should be absorbed by L3.
__global__ __launch_bounds__(512, 2) void fused_kernel(
        const float* __restrict__ x, const int* __restrict__ tgt,
        float* __restrict__ outN, float* __restrict__ outL,
        float* __restrict__ PBsum, int* __restrict__ PBtgt,
        float* __restrict__ rowsum,
        const float* __restrict__ wP, const float* __restrict__ bP) {
    __shared__ float sSum[64];
    __shared__ float sSq[64];
    __shared__ int   sTgt[64];
    __shared__ float s_h[S_];
    __shared__ float c_h[S_];
    __shared__ int   ired[512];

    int tid = threadIdx.x;
    int g   = tid >> 4;                  // 32 groups of 16 lanes
    int li  = tid & 15;
    int r0  = blockIdx.x * 64 + g * 2;
    int r1  = r0 + 1;

    if (blockIdx.x == 0 && tid == 0) atomicExch(outL, 0.f);

    const fx4* __restrict__ xa = (const fx4*)(x + (size_t)r0 * E_);
    const fx4* __restrict__ xb = (const fx4*)(x + (size_t)r1 * E_);
    fx4* __restrict__ oa = (fx4*)(outN + (size_t)r0 * E_);
    fx4* __restrict__ ob = (fx4*)(outN + (size_t)r1 * E_);

    // 8 independent loads
    fx4 a0 = xa[li];       fx4 a1 = xa[li + 16];
    fx4 a2 = xa[li + 32];  fx4 a3 = xa[li + 48];
    fx4 b0 = xb[li];       fx4 b1 = xb[li + 16];
    fx4 b2 = xb[li + 32];  fx4 b3 = xb[li + 48];

    float sumA = (a0.x+a0.y+a0.z+a0.w)+(a1.x+a1.y+a1.z+a1.w)
               + (a2.x+a2.y+a2.z+a2.w)+(a3.x+a3.y+a3.z+a3.w);
    float sqA  = (a0.x*a0.x+a0.y*a0.y+a0.z*a0.z+a0.w*a0.w)
               + (a1.x*a1.x+a1.y*a1.y+a1.z*a1.z+a1.w*a1.w)
               + (a2.x*a2.x+a2.y*a2.y+a2.z*a2.z+a2.w*a2.w)
               + (a3.x*a3.x+a3.y*a3.y+a3.z*a3.z+a3.w*a3.w);
    float sumB = (b0.x+b0.y+b0.z+b0.w)+(b1.x+b1.y+b1.z+b1.w)
               + (b2.x+b2.y+b2.z+b2.w)+(b3.x+b3.y+b3.z+b3.w);
    float sqB  = (b0.x*b0.x+b0.y*b0.y+b0.z*b0.z+b0.w*b0.w)
               + (b1.x*b1.x+b1.y*b1.y+b1.z*b1.z+b1.w*b1.w)
               + (b2.x*b2.x+b2.y*b2.y+b2.z*b2.z+b2.w*b2.w)
               + (b3.x*b3.x+b3.y*b3.y+b3.z*b3.z+b3.w*b3.w);

    #pragma unroll
    for (int o = 8; o >= 1; o >>= 1) {   // intra-16-lane, 4 chains interleave
        sumA += __shfl_xor(sumA, o, 64);  sqA += __shfl_xor(sqA, o, 64);
        sumB += __shfl_xor(sumB, o, 64);  sqB += __shfl_xor(sqB, o, 64);
    }

    float rnA = 1.0f / fmaxf(sqrtf(sqA), EPS_NORM);
    float rnB = 1.0f / fmaxf(sqrtf(sqB), EPS_NORM);

    oa[li]      = a0 * rnA;
    oa[li + 16] = a1 * rnA;
    oa[li + 32] = a2 * rnA;
    oa[li + 48] = a3 * rnA;
    ob[li]      = b0 * rnB;
    ob[li + 16] = b1 * rnB;
    ob[li + 32] = b2 * rnB;
    ob[li + 48] = b3 * rnB;

    if (li == 0) {
        rowsum[r0] = sumA;               // for general fallback only
        rowsum[r1] = sumB;
        sSum[2*g]   = sumA; sSq[2*g]   = sqA; sTgt[2*g]   = tgt[r0];
        sSum[2*g+1] = sumB; sSq[2*g+1] = sqB; sTgt[2*g+1] = tgt[r1];
    }
    __syncthreads();

    // per-32-row-half aggregation by wave 0 -> PB (own slots, non-atomic)
    if (tid < 64) {
        float v = sSum[tid];
        int   t = sTgt[tid];
        int tmn = t, tmx = t;
        float tot = v;
        #pragma unroll
        for (int o = 16; o >= 1; o >>= 1) {
            tot += __shfl_xor(tot, o, 32);
            tmn  = min(tmn, __shfl_xor(tmn, o, 32));
            tmx  = max(tmx, __shfl_xor(tmx, o, 32));
        }
        if ((tid & 31) == 0) {
            int h = tid >> 5;
            PBsum[blockIdx.x * 2 + h] = tot;
            PBtgt[blockIdx.x * 2 + h] = (tmn == tmx) ? tmn : -1;
        }
    }

    cg::grid_group grid = cg::this_grid();
    grid.sync();                         // the ONLY grid-wide sync

    // ---- Phase C ----
    s_h[tid] = 0.f; s_h[tid + 512] = 0.f;
    c_h[tid] = 0.f; c_h[tid + 512] = 0.f;
    int f0 = PBtgt[2 * tid];
    int f1 = PBtgt[2 * tid + 1];
    float p0 = PBsum[2 * tid];
    float p1 = PBsum[2 * tid + 1];
    ired[tid] = ((f0 | f1) < 0) ? 1 : 0;
    __syncthreads();
    #pragma unroll
    for (int st = 256; st > 0; st >>= 1) {
        if (tid < st) ired[tid] |= ired[tid + st];
        __syncthreads();
    }
    bool slow = (ired[0] != 0);

    if (!slow) {                         // balanced/clustered: 2 LDS adds/thr
        atomicAdd(&s_h[f0], p0);  atomicAdd(&c_h[f0], 32.0f);
        atomicAdd(&s_h[f1], p1);  atomicAdd(&c_h[f1], 32.0f);
    } else {                             // general: full segment-sum
        for (int i = tid; i < B_; i += 512) {
            int t = tgt[i];
            atomicAdd(&s_h[t], rowsum[i]);
            atomicAdd(&c_h[t], 1.0f);
        }
    }
    __syncthreads();

    int packed = 0;   // (npos << 16) | nneg
    {
        float cv0 = s_h[tid] / c_h[tid];
        float cv1 = s_h[tid + 512] / c_h[tid + 512];
        if (fabsf(cv0) * 16.0f >= EPS_COS) packed += (cv0 > 0.f) ? (1 << 16) : 1;
        if (fabsf(cv1) * 16.0f >= EPS_COS) packed += (cv1 > 0.f) ? (1 << 16) : 1;
    }
    ired[tid] = packed;
    __syncthreads();
    #pragma unroll
    for (int st = 256; st > 0; st >>= 1) {
        if (tid < st) ired[tid] += ired[tid + st];
        __syncthreads();
    }
    int npos = ired[0] >> 16, nneg = ired[0] & 0xFFFF;

    if (tid < 64) {
        float w  = wP[0], b = bP[0];
        float wr = fmaxf(w, 0.f);

        int   t  = sTgt[tid];
        float rs = sSum[tid], sq = sSq[tid];
        float sj = s_h[t],    nj = c_h[t];

        float nem = fmaxf(sqrtf(sq), EPS_COS);

        float dot = (sj * rs - sq) / nj;
        float nc  = sqrtf((float)E_ * sj * sj - 2.f * sj * rs + sq) / nj;
        float self_cos = dot / (nem * fmaxf(nc, EPS_COS));
        float self_sim = wr * self_cos + b;

        float A  = wr * rs / (nem * 16.0f);
        float xp =  A + b, xm = -A + b, xz = b;

        float ct = sj / nj;
        int np = npos, nm = nneg, nz = S_ - npos - nneg;
        if (fabsf(ct) * 16.0f >= EPS_COS) { if (ct > 0.f) np--; else nm--; }
        else nz--;

        float m = self_sim;
        if (np > 0) m = fmaxf(m, xp);
        if (nm > 0) m = fmaxf(m, xm);
        if (nz > 0) m = fmaxf(m, xz);
        float ssum = expf(self_sim - m)
                   + (float)np * expf(xp - m)
                   + (float)nm * expf(xm - m)
                   + (float)nz * expf(xz - m);
        float contrib = m + logf(ssum) - self_sim;

        #pragma unroll
        for (int o = 32; o >= 1; o >>= 1)
            contrib += __shfl_xor(contrib, o, 64);
        if (tid == 0) atomicAdd(outL, contrib);
    }
}

// =================== fallback path (proven R5 kernels) =====================
__global__ void zero_ws_kernel(float* s, float* cnt, float* outL) {
    int i = blockIdx.x * blockDim.x + threadIdx.x;
    if (i < S_) { s[i] = 0.f; cnt[i] = 0.f; }
    if (i == 0) outL[0] = 0.f;
}

__global__ __launch_bounds__(256) void rows_kernel(
        const float* __restrict__ x, const int* __restrict__ tgt,
        float* __restrict__ outN,
        float* __restrict__ rowsum, float* __restrict__ sqsum,
        float* __restrict__ s, float* __restrict__ cnt) {
    int wave = threadIdx.x >> 6;
    int lane = threadIdx.x & 63;
    int li   = lane & 15;
    int sub  = lane >> 4;
    int rowA = blockIdx.x * 32 + wave * 8 + sub * 2;
    int rowB = rowA + 1;

    const fx4* __restrict__ xa = (const fx4*)(x + (size_t)rowA * E_);
    const fx4* __restrict__ xb = (const fx4*)(x + (size_t)rowB * E_);
    fx4* __restrict__ oa = (fx4*)(outN + (size_t)rowA * E_);
    fx4* __restrict__ ob = (fx4*)(outN + (size_t)rowB * E_);

    fx4 a0 = xa[li]; fx4 a1 = xa[li + 16]; fx4 a2 = xa[li + 32]; fx4 a3 = xa[li + 48];
    fx4 b0 = xb[li]; fx4 b1 = xb[li + 16]; fx4 b2 = xb[li + 32]; fx4 b3 = xb[li + 48];

    float sumA = (a0.x+a0.y+a0.z+a0.w)+(a1.x+a1.y+a1.z+a1.w)
               + (a2.x+a2.y+a2.z+a2.w)+(a3.x+a3.y+a3.z+a3.w);
    float sqA  = (a0.x*a0.x+a0.y*a0.y+a0.z*a0.z+a0.w*a0.w)
               + (a1.x*a1.x+a1.y*a1.y+a1.z*a1.z+a1.w*a1.w)
               + (a2.x*a2.x+a2.y*a2.y+a2.z*a2.z+a2.w*a2.w)
               + (a3.x*a3.x+a3.y*a3.y+a3.z*a3.z+a3.w*a3.w);
    float sumB = (b0.x+b0.y+b0.z+b0.w)+(b1.x+b1.y+b1.z+b1.w)
               + (b2.x+b2.y+b2.z+b2.w)+(b3.x+b3.y+b3.z+b3.w);
    float sqB  = (b0.x*b0.x+b0.y*b0.y+b0.z*b0.z+b0.w*b0.w)
               + (b1.x*b1.x+b1.y*b1.y+b1.z*b1.z+b1.w*b1.w)
               + (b2.x*b2.x+b2.y*b2.y+b2.z*b2.z+b2.w*b2.w)
               + (b3.x*b3.x+b3.y*b3.y+b3.z*b3.z+b3.w*b3.w);

    #pragma unroll
    for (int o = 8; o >= 1; o >>= 1) {
        sumA += __shfl_xor(sumA, o, 64); sqA += __shfl_xor(sqA, o, 64);
        sumB += __shfl_xor(sumB, o, 64); sqB += __shfl_xor(sqB, o, 64);
    }

    float rnA = 1.0f / fmaxf(sqrtf(sqA), EPS_NORM);
    float rnB = 1.0f / fmaxf(sqrtf(sqB), EPS_NORM);

    oa[li]      = a0 * rnA;
    oa[li + 16] = a1 * rnA;
    oa[li + 32] = a2 * rnA;
    oa[li + 48] = a3 * rnA;
    ob[li]      = b0 * rnB;
    ob[li + 16] = b1 * rnB;
    ob[li + 32] = b2 * rnB;
    ob[li + 48] = b3 * rnB;

    __shared__ float sSum[32];
    __shared__ int   sTgt[32];
    if (li == 0) {
        rowsum[rowA] = sumA; sqsum[rowA] = sqA;
        rowsum[rowB] = sumB; sqsum[rowB] = sqB;
        int slot = wave * 8 + sub * 2;
        sSum[slot] = sumA; sSum[slot + 1] = sumB;
        sTgt[slot] = tgt[rowA]; sTgt[slot + 1] = tgt[rowB];
    }
    __syncthreads();
    if (threadIdx.x < 32) {
        float v = sSum[threadIdx.x];
        int   t = sTgt[threadIdx.x];
        int tmn = t, tmx = t;
        float tot = v;
        #pragma unroll
        for (int o = 16; o >= 1; o >>= 1) {
            tot += __shfl_xor(tot, o, 32);
            tmn  = min(tmn, __shfl_xor(tmn, o, 32));
            tmx  = max(tmx, __shfl_xor(tmx, o, 32));
        }
        if (tmn == tmx) {
            if (threadIdx.x == 0) { atomicAdd(&s[t], tot); atomicAdd(&cnt[t], 32.0f); }
        } else {
            atomicAdd(&s[t], v); atomicAdd(&cnt[t], 1.0f);
        }
    }
}

__global__ __launch_bounds__(256) void loss_kernel(
        const float* __restrict__ rowsum, const float* __restrict__ sqsum,
        const int* __restrict__ tgt,
        const float* __restrict__ s, const float* __restrict__ cnt,
        const float* __restrict__ wP, const float* __restrict__ bP,
        float* __restrict__ outL) {
    int packed = 0;
    #pragma unroll
    for (int j = 0; j < S_ / 256; ++j) {
        int k = threadIdx.x * (S_ / 256) + j;
        float cv = s[k] / cnt[k];
        if (fabsf(cv) * 16.0f >= EPS_COS) packed += (cv > 0.f) ? (1 << 16) : 1;
    }
    __shared__ int ired[256];
    ired[threadIdx.x] = packed;
    __syncthreads();
    #pragma unroll
    for (int st = 128; st > 0; st >>= 1) {
        if (threadIdx.x < st) ired[threadIdx.x] += ired[threadIdx.x + st];
        __syncthreads();
    }
    int npos = ired[0] >> 16, nneg = ired[0] & 0xFFFF;

    int i = blockIdx.x * blockDim.x + threadIdx.x;
    float w  = wP[0], b = bP[0];
    float wr = fmaxf(w, 0.f);

    int   t  = tgt[i];
    float rs = rowsum[i], sq = sqsum[i];
    float sj = s[t],      nj = cnt[t];

    float nem = fmaxf(sqrtf(sq), EPS_COS);
    float dot = (sj * rs - sq) / nj;
    float nc  = sqrtf((float)E_ * sj * sj - 2.f * sj * rs + sq) / nj;
    float self_cos = dot / (nem * fmaxf(nc, EPS_COS));
    float self_sim = wr * self_cos + b;

    float A  = wr * rs / (nem * 16.0f);
    float xp =  A + b, xm = -A + b, xz = b;

    float ct = sj / nj;
    int np = npos, nm = nneg, nz = S_ - npos - nneg;
    if (fabsf(ct) * 16.0f >= EPS_COS) { if (ct > 0.f) np--; else nm--; }
    else nz--;

    float m = self_sim;
    if (np > 0) m = fmaxf(m, xp);
    if (nm > 0) m = fmaxf(m, xm);
    if (nz > 0) m = fmaxf(m, xz);
    float ssum = expf(self_sim - m)
               + (float)np * expf(xp - m)
               + (float)nm * expf(xm - m)
               + (float)nz * expf(xz - m);
    float contrib = m + logf(ssum) - self_sim;

    __shared__ float fred[256];
    fred[threadIdx.x] = contrib;
    __syncthreads();
    #pragma unroll
    for (int st = 128; st > 0; st >>= 1) {
        if (threadIdx.x < st) fred[threadIdx.x] += fred[threadIdx.x + st];
        __syncthreads();
    }
    if (threadIdx.x == 0) atomicAdd(outL, fred[0]);
}

extern "C" void kernel_launch(void* const* d_in, const int* in_sizes, int n_in,
                              void* d_out, int out_size, void* d_ws, size_t ws_size,
                              hipStream_t stream) {
    const float* inputs  = (const float*)d_in[0];
    const int*   targets = (const int*)d_in[1];
    const float* wP      = (const float*)d_in[2];
    const float* bP      = (const float*)d_in[3];
    float* outN = (float*)d_out;                    // [B,E] normalized
    float* outL = (float*)d_out + (size_t)B_ * E_;  // [1] loss

    float* wsf    = (float*)d_ws;
    float* rowsum = wsf;                 // B
    float* sqsum  = wsf + B_;            // B (fallback path only)
    float* sArr   = wsf + 2 * B_;        // S (fallback path only)
    float* cntArr = sArr + S_;           // S (fallback path only)
    float* PBsum  = cntArr + S_;         // 1024
    int*   PBtgt  = (int*)(PBsum + 1024);// 1024

    int nb = 0;
    hipOccupancyMaxActiveBlocksPerMultiprocessor(&nb, fused_kernel, 512, 0);

    if (nb >= 2) {   // 512 blocks co-resident on 256 CUs -> cooperative OK
        void* args[] = { (void*)&inputs, (void*)&targets, (void*)&outN,
                         (void*)&outL, (void*)&PBsum, (void*)&PBtgt,
                         (void*)&rowsum, (void*)&wP, (void*)&bP };
        hipLaunchCooperativeKernel((void*)fused_kernel, dim3(512),
                                   dim3(512), args, 0, stream);
    } else {         // deterministic fallback: proven 3-kernel path
        zero_ws_kernel<<<S_ / 256, 256, 0, stream>>>(sArr, cntArr, outL);
        rows_kernel<<<B_ / 32, 256, 0, stream>>>(inputs, targets, outN,
                                                 rowsum, sqsum, sArr, cntArr);
        loss_kernel<<<B_ / 256, 256, 0, stream>>>(rowsum, sqsum, targets,
                                                  sArr, cntArr, wP, bP, outL);
    }
}

// Round 10
// 24.319 us; speedup vs baseline: 1.0942x; 1.0942x over previous
//
#include <hip/hip_runtime.h>
#include <hip/hip_cooperative_groups.h>
#include <math.h>

#define B_ 32768
#define E_ 256
#define S_ 1024
#define EPS_COS 1e-8f
#define EPS_NORM 1e-12f

typedef float fx4 __attribute__((ext_vector_type(4)));

namespace cg = cooperative_groups;

// =================== fused cooperative kernel (v4) =========================
// Grid = 512 blocks x 512 threads. Block b owns rows [64b, 64b+64).
// Phase A: row sums + normalized NT stores; per-32-row-half partials -> PB.
// ONE grid.sync.
// Phase C (fast): balanced layout => PBtgt[i]==i, s[k]=PBsum[k], n[k]=32.
//   Sign buckets via ballot/popcount (1 barrier), 64 row losses, 1 atomic.
// Phase C (slow): full LDS histogram from rowsum/tgt (block-uniform branch).
__global__ __launch_bounds__(512, 2) void fused_kernel(
        const float* __restrict__ x, const int* __restrict__ tgt,
        float* __restrict__ outN, float* __restrict__ outL,
        float* __restrict__ PBsum, int* __restrict__ PBtgt,
        float* __restrict__ rowsum,
        const float* __restrict__ wP, const float* __restrict__ bP) {
    __shared__ float sSum[64];
    __shared__ float sSq[64];
    __shared__ int   sTgt[64];
    __shared__ int   wS[8][3];          // per-wave {npos, nneg, badflag}
    __shared__ float s_h[S_];           // slow path only
    __shared__ float c_h[S_];           // slow path only

    int tid = threadIdx.x;
    int g   = tid >> 4;                  // 32 groups of 16 lanes
    int li  = tid & 15;
    int r0  = blockIdx.x * 64 + g * 2;
    int r1  = r0 + 1;

    if (blockIdx.x == 0 && tid == 0) atomicExch(outL, 0.f);

    const fx4* __restrict__ xa = (const fx4*)(x + (size_t)r0 * E_);
    const fx4* __restrict__ xb = (const fx4*)(x + (size_t)r1 * E_);
    fx4* __restrict__ oa = (fx4*)(outN + (size_t)r0 * E_);
    fx4* __restrict__ ob = (fx4*)(outN + (size_t)r1 * E_);

    // 8 independent loads
    fx4 a0 = xa[li];       fx4 a1 = xa[li + 16];
    fx4 a2 = xa[li + 32];  fx4 a3 = xa[li + 48];
    fx4 b0 = xb[li];       fx4 b1 = xb[li + 16];
    fx4 b2 = xb[li + 32];  fx4 b3 = xb[li + 48];

    float sumA = (a0.x+a0.y+a0.z+a0.w)+(a1.x+a1.y+a1.z+a1.w)
               + (a2.x+a2.y+a2.z+a2.w)+(a3.x+a3.y+a3.z+a3.w);
    float sqA  = (a0.x*a0.x+a0.y*a0.y+a0.z*a0.z+a0.w*a0.w)
               + (a1.x*a1.x+a1.y*a1.y+a1.z*a1.z+a1.w*a1.w)
               + (a2.x*a2.x+a2.y*a2.y+a2.z*a2.z+a2.w*a2.w)
               + (a3.x*a3.x+a3.y*a3.y+a3.z*a3.z+a3.w*a3.w);
    float sumB = (b0.x+b0.y+b0.z+b0.w)+(b1.x+b1.y+b1.z+b1.w)
               + (b2.x+b2.y+b2.z+b2.w)+(b3.x+b3.y+b3.z+b3.w);
    float sqB  = (b0.x*b0.x+b0.y*b0.y+b0.z*b0.z+b0.w*b0.w)
               + (b1.x*b1.x+b1.y*b1.y+b1.z*b1.z+b1.w*b1.w)
               + (b2.x*b2.x+b2.y*b2.y+b2.z*b2.z+b2.w*b2.w)
               + (b3.x*b3.x+b3.y*b3.y+b3.z*b3.z+b3.w*b3.w);

    #pragma unroll
    for (int o = 8; o >= 1; o >>= 1) {   // intra-16-lane, 4 chains interleave
        sumA += __shfl_xor(sumA, o, 64);  sqA += __shfl_xor(sqA, o, 64);
        sumB += __shfl_xor(sumB, o, 64);  sqB += __shfl_xor(sqB, o, 64);
    }

    float rnA = 1.0f / fmaxf(sqrtf(sqA), EPS_NORM);
    float rnB = 1.0f / fmaxf(sqrtf(sqB), EPS_NORM);

    __builtin_nontemporal_store(a0 * rnA, &oa[li]);
    __builtin_nontemporal_store(a1 * rnA, &oa[li + 16]);
    __builtin_nontemporal_store(a2 * rnA, &oa[li + 32]);
    __builtin_nontemporal_store(a3 * rnA, &oa[li + 48]);
    __builtin_nontemporal_store(b0 * rnB, &ob[li]);
    __builtin_nontemporal_store(b1 * rnB, &ob[li + 16]);
    __builtin_nontemporal_store(b2 * rnB, &ob[li + 32]);
    __builtin_nontemporal_store(b3 * rnB, &ob[li + 48]);

    if (li == 0) {
        rowsum[r0] = sumA;               // for slow path only
        rowsum[r1] = sumB;
        sSum[2*g]   = sumA; sSq[2*g]   = sqA; sTgt[2*g]   = tgt[r0];
        sSum[2*g+1] = sumB; sSq[2*g+1] = sqB; sTgt[2*g+1] = tgt[r1];
    }
    __syncthreads();

    // per-32-row-half aggregation by wave 0 -> PB (own slots, non-atomic)
    if (tid < 64) {
        float v = sSum[tid];
        int   t = sTgt[tid];
        int tmn = t, tmx = t;
        float tot = v;
        #pragma unroll
        for (int o = 16; o >= 1; o >>= 1) {
            tot += __shfl_xor(tot, o, 32);
            tmn  = min(tmn, __shfl_xor(tmn, o, 32));
            tmx  = max(tmx, __shfl_xor(tmx, o, 32));
        }
        if ((tid & 31) == 0) {
            int h = tid >> 5;
            PBsum[blockIdx.x * 2 + h] = tot;
            PBtgt[blockIdx.x * 2 + h] = (tmn == tmx) ? tmn : -1;
        }
    }

    cg::grid_group grid = cg::this_grid();
    grid.sync();                         // the ONLY grid-wide sync

    // ---- Phase C ----
    int   i0 = 2 * tid, i1 = i0 + 1;
    int   f0 = PBtgt[i0],  f1 = PBtgt[i1];
    float p0 = PBsum[i0],  p1 = PBsum[i1];
    bool fastok = (f0 == i0) && (f1 == i1);   // balanced layout identity

    float cv0 = p0 * (1.0f / 32.0f);
    float cv1 = p1 * (1.0f / 32.0f);
    unsigned long long bad = __ballot(!fastok);
    unsigned long long bp0 = __ballot(fabsf(cv0) * 16.0f >= EPS_COS && cv0 > 0.f);
    unsigned long long bn0 = __ballot(fabsf(cv0) * 16.0f >= EPS_COS && !(cv0 > 0.f));
    unsigned long long bp1 = __ballot(fabsf(cv1) * 16.0f >= EPS_COS && cv1 > 0.f);
    unsigned long long bn1 = __ballot(fabsf(cv1) * 16.0f >= EPS_COS && !(cv1 > 0.f));
    int wv = tid >> 6;
    if ((tid & 63) == 0) {
        wS[wv][0] = (int)__popcll(bp0) + (int)__popcll(bp1);
        wS[wv][1] = (int)__popcll(bn0) + (int)__popcll(bn1);
        wS[wv][2] = (bad != 0ull) ? 1 : 0;
    }
    __syncthreads();
    int npos = 0, nneg = 0, slowf = 0;
    #pragma unroll
    for (int k = 0; k < 8; ++k) {
        npos += wS[k][0]; nneg += wS[k][1]; slowf |= wS[k][2];
    }

    if (slowf) {                         // ---- general slow path ----
        s_h[i0] = 0.f; s_h[i1] = 0.f;
        c_h[i0] = 0.f; c_h[i1] = 0.f;
        __syncthreads();
        for (int i = tid; i < B_; i += 512) {
            int t = tgt[i];
            atomicAdd(&s_h[t], rowsum[i]);
            atomicAdd(&c_h[t], 1.0f);
        }
        __syncthreads();
        float d0 = s_h[i0] / c_h[i0];
        float d1 = s_h[i1] / c_h[i1];
        unsigned long long sp0 = __ballot(fabsf(d0) * 16.0f >= EPS_COS && d0 > 0.f);
        unsigned long long sn0 = __ballot(fabsf(d0) * 16.0f >= EPS_COS && !(d0 > 0.f));
        unsigned long long sp1 = __ballot(fabsf(d1) * 16.0f >= EPS_COS && d1 > 0.f);
        unsigned long long sn1 = __ballot(fabsf(d1) * 16.0f >= EPS_COS && !(d1 > 0.f));
        if ((tid & 63) == 0) {
            wS[wv][0] = (int)__popcll(sp0) + (int)__popcll(sp1);
            wS[wv][1] = (int)__popcll(sn0) + (int)__popcll(sn1);
        }
        __syncthreads();
        npos = 0; nneg = 0;
        #pragma unroll
        for (int k = 0; k < 8; ++k) { npos += wS[k][0]; nneg += wS[k][1]; }
    }

    // per-row loss for the block's 64 rows (wave 0)
    if (tid < 64) {
        float w  = wP[0], b = bP[0];
        float wr = fmaxf(w, 0.f);

        int   t  = sTgt[tid];
        float rs = sSum[tid], sq = sSq[tid];
        float sj, nj;
        if (slowf) { sj = s_h[t]; nj = c_h[t]; }
        else       { sj = PBsum[t]; nj = 32.0f; }

        float nem = fmaxf(sqrtf(sq), EPS_COS);

        float dot = (sj * rs - sq) / nj;
        float nc  = sqrtf((float)E_ * sj * sj - 2.f * sj * rs + sq) / nj;
        float self_cos = dot / (nem * fmaxf(nc, EPS_COS));
        float self_sim = wr * self_cos + b;

        float A  = wr * rs / (nem * 16.0f);
        float xp =  A + b, xm = -A + b, xz = b;

        float ct = sj / nj;
        int np = npos, nm = nneg, nz = S_ - npos - nneg;
        if (fabsf(ct) * 16.0f >= EPS_COS) { if (ct > 0.f) np--; else nm--; }
        else nz--;

        float m = self_sim;
        if (np > 0) m = fmaxf(m, xp);
        if (nm > 0) m = fmaxf(m, xm);
        if (nz > 0) m = fmaxf(m, xz);
        float ssum = expf(self_sim - m)
                   + (float)np * expf(xp - m)
                   + (float)nm * expf(xm - m)
                   + (float)nz * expf(xz - m);
        float contrib = m + logf(ssum) - self_sim;

        #pragma unroll
        for (int o = 32; o >= 1; o >>= 1)
            contrib += __shfl_xor(contrib, o, 64);
        if (tid == 0) atomicAdd(outL, contrib);
    }
}

// =================== fallback path (proven R5 kernels) =====================
__global__ void zero_ws_kernel(float* s, float* cnt, float* outL) {
    int i = blockIdx.x * blockDim.x + threadIdx.x;
    if (i < S_) { s[i] = 0.f; cnt[i] = 0.f; }
    if (i == 0) outL[0] = 0.f;
}

__global__ __launch_bounds__(256) void rows_kernel(
        const float* __restrict__ x, const int* __restrict__ tgt,
        float* __restrict__ outN,
        float* __restrict__ rowsum, float* __restrict__ sqsum,
        float* __restrict__ s, float* __restrict__ cnt) {
    int wave = threadIdx.x >> 6;
    int lane = threadIdx.x & 63;
    int li   = lane & 15;
    int sub  = lane >> 4;
    int rowA = blockIdx.x * 32 + wave * 8 + sub * 2;
    int rowB = rowA + 1;

    const fx4* __restrict__ xa = (const fx4*)(x + (size_t)rowA * E_);
    const fx4* __restrict__ xb = (const fx4*)(x + (size_t)rowB * E_);
    fx4* __restrict__ oa = (fx4*)(outN + (size_t)rowA * E_);
    fx4* __restrict__ ob = (fx4*)(outN + (size_t)rowB * E_);

    fx4 a0 = xa[li]; fx4 a1 = xa[li + 16]; fx4 a2 = xa[li + 32]; fx4 a3 = xa[li + 48];
    fx4 b0 = xb[li]; fx4 b1 = xb[li + 16]; fx4 b2 = xb[li + 32]; fx4 b3 = xb[li + 48];

    float sumA = (a0.x+a0.y+a0.z+a0.w)+(a1.x+a1.y+a1.z+a1.w)
               + (a2.x+a2.y+a2.z+a2.w)+(a3.x+a3.y+a3.z+a3.w);
    float sqA  = (a0.x*a0.x+a0.y*a0.y+a0.z*a0.z+a0.w*a0.w)
               + (a1.x*a1.x+a1.y*a1.y+a1.z*a1.z+a1.w*a1.w)
               + (a2.x*a2.x+a2.y*a2.y+a2.z*a2.z+a2.w*a2.w)
               + (a3.x*a3.x+a3.y*a3.y+a3.z*a3.z+a3.w*a3.w);
    float sumB = (b0.x+b0.y+b0.z+b0.w)+(b1.x+b1.y+b1.z+b1.w)
               + (b2.x+b2.y+b2.z+b2.w)+(b3.x+b3.y+b3.z+b3.w);
    float sqB  = (b0.x*b0.x+b0.y*b0.y+b0.z*b0.z+b0.w*b0.w)
               + (b1.x*b1.x+b1.y*b1.y+b1.z*b1.z+b1.w*b1.w)
               + (b2.x*b2.x+b2.y*b2.y+b2.z*b2.z+b2.w*b2.w)
               + (b3.x*b3.x+b3.y*b3.y+b3.z*b3.z+b3.w*b3.w);

    #pragma unroll
    for (int o = 8; o >= 1; o >>= 1) {
        sumA += __shfl_xor(sumA, o, 64); sqA += __shfl_xor(sqA, o, 64);
        sumB += __shfl_xor(sumB, o, 64); sqB += __shfl_xor(sqB, o, 64);
    }

    float rnA = 1.0f / fmaxf(sqrtf(sqA), EPS_NORM);
    float rnB = 1.0f / fmaxf(sqrtf(sqB), EPS_NORM);

    __builtin_nontemporal_store(a0 * rnA, &oa[li]);
    __builtin_nontemporal_store(a1 * rnA, &oa[li + 16]);
    __builtin_nontemporal_store(a2 * rnA, &oa[li + 32]);
    __builtin_nontemporal_store(a3 * rnA, &oa[li + 48]);
    __builtin_nontemporal_store(b0 * rnB, &ob[li]);
    __builtin_nontemporal_store(b1 * rnB, &ob[li + 16]);
    __builtin_nontemporal_store(b2 * rnB, &ob[li + 32]);
    __builtin_nontemporal_store(b3 * rnB, &ob[li + 48]);

    __shared__ float sSum[32];
    __shared__ int   sTgt[32];
    if (li == 0) {
        rowsum[rowA] = sumA; sqsum[rowA] = sqA;
        rowsum[rowB] = sumB; sqsum[rowB] = sqB;
        int slot = wave * 8 + sub * 2;
        sSum[slot] = sumA; sSum[slot + 1] = sumB;
        sTgt[slot] = tgt[rowA]; sTgt[slot + 1] = tgt[rowB];
    }
    __syncthreads();
    if (threadIdx.x < 32) {
        float v = sSum[threadIdx.x];
        int   t = sTgt[threadIdx.x];
        int tmn = t, tmx = t;
        float tot = v;
        #pragma unroll
        for (int o = 16; o >= 1; o >>= 1) {
            tot += __shfl_xor(tot, o, 32);
            tmn  = min(tmn, __shfl_xor(tmn, o, 32));
            tmx  = max(tmx, __shfl_xor(tmx, o, 32));
        }
        if (tmn == tmx) {
            if (threadIdx.x == 0) { atomicAdd(&s[t], tot); atomicAdd(&cnt[t], 32.0f); }
        } else {
            atomicAdd(&s[t], v); atomicAdd(&cnt[t], 1.0f);
        }
    }
}

__global__ __launch_bounds__(256) void loss_kernel(
        const float* __restrict__ rowsum, const float* __restrict__ sqsum,
        const int* __restrict__ tgt,
        const float* __restrict__ s, const float* __restrict__ cnt,
        const float* __restrict__ wP, const float* __restrict__ bP,
        float* __restrict__ outL) {
    int packed = 0;
    #pragma unroll
    for (int j = 0; j < S_ / 256; ++j) {
        int k = threadIdx.x * (S_ / 256) + j;
        float cv = s[k] / cnt[k];
        if (fabsf(cv) * 16.0f >= EPS_COS) packed += (cv > 0.f) ? (1 << 16) : 1;
    }
    __shared__ int ired[256];
    ired[threadIdx.x] = packed;
    __syncthreads();
    #pragma unroll
    for (int st = 128; st > 0; st >>= 1) {
        if (threadIdx.x < st) ired[threadIdx.x] += ired[threadIdx.x + st];
        __syncthreads();
    }
    int npos = ired[0] >> 16, nneg = ired[0] & 0xFFFF;

    int i = blockIdx.x * blockDim.x + threadIdx.x;
    float w  = wP[0], b = bP[0];
    float wr = fmaxf(w, 0.f);

    int   t  = tgt[i];
    float rs = rowsum[i], sq = sqsum[i];
    float sj = s[t],      nj = cnt[t];

    float nem = fmaxf(sqrtf(sq), EPS_COS);
    float dot = (sj * rs - sq) / nj;
    float nc  = sqrtf((float)E_ * sj * sj - 2.f * sj * rs + sq) / nj;
    float self_cos = dot / (nem * fmaxf(nc, EPS_COS));
    float self_sim = wr * self_cos + b;

    float A  = wr * rs / (nem * 16.0f);
    float xp =  A + b, xm = -A + b, xz = b;

    float ct = sj / nj;
    int np = npos, nm = nneg, nz = S_ - npos - nneg;
    if (fabsf(ct) * 16.0f >= EPS_COS) { if (ct > 0.f) np--; else nm--; }
    else nz--;

    float m = self_sim;
    if (np > 0) m = fmaxf(m, xp);
    if (nm > 0) m = fmaxf(m, xm);
    if (nz > 0) m = fmaxf(m, xz);
    float ssum = expf(self_sim - m)
               + (float)np * expf(xp - m)
               + (float)nm * expf(xm - m)
               + (float)nz * expf(xz - m);
    float contrib = m + logf(ssum) - self_sim;

    __shared__ float fred[256];
    fred[threadIdx.x] = contrib;
    __syncthreads();
    #pragma unroll
    for (int st = 128; st > 0; st >>= 1) {
        if (threadIdx.x < st) fred[threadIdx.x] += fred[threadIdx.x + st];
        __syncthreads();
    }
    if (threadIdx.x == 0) atomicAdd(outL, fred[0]);
}

extern "C" void kernel_launch(void* const* d_in, const int* in_sizes, int n_in,
                              void* d_out, int out_size, void* d_ws, size_t ws_size,
                              hipStream_t stream) {
    const float* inputs  = (const float*)d_in[0];
    const int*   targets = (const int*)d_in[1];
    const float* wP      = (const float*)d_in[2];
    const float* bP      = (const float*)d_in[3];
    float* outN = (float*)d_out;                    // [B,E] normalized
    float* outL = (float*)d_out + (size_t)B_ * E_;  // [1] loss

    float* wsf    = (float*)d_ws;
    float* rowsum = wsf;                 // B
    float* sqsum  = wsf + B_;            // B (fallback path only)
    float* sArr   = wsf + 2 * B_;        // S (fallback path only)
    float* cntArr = sArr + S_;           // S (fallback path only)
    float* PBsum  = cntArr + S_;         // 1024
    int*   PBtgt  = (int*)(PBsum + 1024);// 1024

    int nb = 0;
    hipOccupancyMaxActiveBlocksPerMultiprocessor(&nb, fused_kernel, 512, 0);

    if (nb >= 2) {   // 512 blocks co-resident on 256 CUs -> cooperative OK
        void* args[] = { (void*)&inputs, (void*)&targets, (void*)&outN,
                         (void*)&outL, (void*)&PBsum, (void*)&PBtgt,
                         (void*)&rowsum, (void*)&wP, (void*)&bP };
        hipLaunchCooperativeKernel((void*)fused_kernel, dim3(512),
                                   dim3(512), args, 0, stream);
    } else {         // deterministic fallback: proven 3-kernel path
        zero_ws_kernel<<<S_ / 256, 256, 0, stream>>>(sArr, cntArr, outL);
        rows_kernel<<<B_ / 32, 256, 0, stream>>>(inputs, targets, outN,
                                                 rowsum, sqsum, sArr, cntArr);
        loss_kernel<<<B_ / 256, 256, 0, stream>>>(rowsum, sqsum, targets,
                                                  sArr, cntArr, wP, bP, outL);
    }
}

// Round 11
// 20.686 us; speedup vs baseline: 1.2864x; 1.1756x over previous
//
#include <hip/hip_runtime.h>
#include <math.h>

#define B_ 32768
#define E_ 256
#define S_ 1024
#define EPS_COS 1e-8f
#define EPS_NORM 1e-12f

typedef float fx4 __attribute__((ext_vector_type(4)));

// ---------------- kernel 1: rows (oversubscribed, streamed) ----------------
// 4096 blocks x 256 threads, 8 rows/block: one row per 32-lane group.
// 2 fx4 loads/lane, 5-level intra-32 butterfly, NT stores.
// Per-block partial (sum over 8 rows, uniform target or -1) -> PB[b].
__global__ __launch_bounds__(256) void rows_kernel(
        const float* __restrict__ x, const int* __restrict__ tgt,
        float* __restrict__ outN, float* __restrict__ outL,
        float* __restrict__ rowsum, float* __restrict__ sqsum,
        float* __restrict__ PBsum, int* __restrict__ PBtgt) {
    __shared__ float sSum[8];
    __shared__ int   sTgt[8];

    int tid = threadIdx.x;
    int g   = tid >> 5;                 // 8 groups of 32 lanes
    int l   = tid & 31;
    int row = blockIdx.x * 8 + g;

    if (blockIdx.x == 0 && tid == 0) outL[0] = 0.f;

    const fx4* __restrict__ xr = (const fx4*)(x + (size_t)row * E_);
    fx4* __restrict__ orow = (fx4*)(outN + (size_t)row * E_);

    fx4 a0 = xr[l];
    fx4 a1 = xr[l + 32];

    float sum = (a0.x + a0.y + a0.z + a0.w) + (a1.x + a1.y + a1.z + a1.w);
    float sq  = (a0.x*a0.x + a0.y*a0.y + a0.z*a0.z + a0.w*a0.w)
              + (a1.x*a1.x + a1.y*a1.y + a1.z*a1.z + a1.w*a1.w);

    #pragma unroll
    for (int o = 16; o >= 1; o >>= 1) { // stays within aligned 32-lane group
        sum += __shfl_xor(sum, o, 64);
        sq  += __shfl_xor(sq,  o, 64);
    }

    float rn = 1.0f / fmaxf(sqrtf(sq), EPS_NORM);
    __builtin_nontemporal_store(a0 * rn, &orow[l]);
    __builtin_nontemporal_store(a1 * rn, &orow[l + 32]);

    if (l == 0) {
        rowsum[row] = sum;
        sqsum[row]  = sq;
        sSum[g] = sum;
        sTgt[g] = tgt[row];
    }
    __syncthreads();
    if (tid == 0) {
        float tot = 0.f;
        int t0 = sTgt[0];
        int same = 1;
        #pragma unroll
        for (int k = 0; k < 8; ++k) {
            tot += sSum[k];
            same &= (sTgt[k] == t0);
        }
        PBsum[blockIdx.x] = tot;
        PBtgt[blockIdx.x] = same ? t0 : -1;
    }
}

// ---------------- kernel 2: loss -------------------------------------------
// 128 blocks x 256 threads; block handles rows [256b, 256b+256).
// Fast path: PBtgt[i]==i>>2 for all i  =>  s[k]=sum of 4 PB entries, n=32.
// Slow path: rebuild full histogram from rowsum/tgt with LDS atomics.
__global__ __launch_bounds__(256) void loss_kernel(
        const float* __restrict__ rowsum, const float* __restrict__ sqsum,
        const int* __restrict__ tgt,
        const float* __restrict__ PBsum, const int* __restrict__ PBtgt,
        const float* __restrict__ wP, const float* __restrict__ bP,
        float* __restrict__ outL) {
    __shared__ float s_h[S_];
    __shared__ float c_h[S_];
    __shared__ int   ired[256];
    __shared__ float fred[256];

    int tid = threadIdx.x;

    // build s_h from PB (4 speakers per thread) + fast-path check + buckets
    int packed = 0;     // (npos<<16) | nneg
    int bad = 0;
    #pragma unroll
    for (int j = 0; j < 4; ++j) {
        int k = tid * 4 + j;
        float sk = PBsum[4*k] + PBsum[4*k+1] + PBsum[4*k+2] + PBsum[4*k+3];
        int ok = (PBtgt[4*k] == k) & (PBtgt[4*k+1] == k)
               & (PBtgt[4*k+2] == k) & (PBtgt[4*k+3] == k);
        bad |= !ok;
        s_h[k] = sk;
        c_h[k] = 32.0f;
        float cv = sk * (1.0f / 32.0f);
        if (fabsf(cv) * 16.0f >= EPS_COS) packed += (cv > 0.f) ? (1 << 16) : 1;
    }
    ired[tid] = packed | (bad ? (1 << 15) : 0);   // bit15 = bad flag (nneg<=1024 fits 11 bits)
    __syncthreads();
    #pragma unroll
    for (int st = 128; st > 0; st >>= 1) {
        if (tid < st) {
            int a = ired[tid], b = ired[tid + st];
            // sum counts, OR the bad bit
            ired[tid] = ((a + b) & ~(1 << 15)) | ((a | b) & (1 << 15));
        }
        __syncthreads();
    }
    int agg  = ired[0];
    int slow = (agg >> 15) & 1;
    int npos = (agg >> 16) & 0xFFFF;
    int nneg = agg & 0x7FFF;

    if (slow) {   // ---- general path: rebuild histogram from rows ----
        __syncthreads();
        s_h[tid] = 0.f; s_h[tid + 256] = 0.f; s_h[tid + 512] = 0.f; s_h[tid + 768] = 0.f;
        c_h[tid] = 0.f; c_h[tid + 256] = 0.f; c_h[tid + 512] = 0.f; c_h[tid + 768] = 0.f;
        __syncthreads();
        for (int i = tid; i < B_; i += 256) {
            int t = tgt[i];
            atomicAdd(&s_h[t], rowsum[i]);
            atomicAdd(&c_h[t], 1.0f);
        }
        __syncthreads();
        packed = 0;
        #pragma unroll
        for (int j = 0; j < 4; ++j) {
            int k = tid * 4 + j;
            float cv = s_h[k] / c_h[k];
            if (fabsf(cv) * 16.0f >= EPS_COS) packed += (cv > 0.f) ? (1 << 16) : 1;
        }
        ired[tid] = packed;
        __syncthreads();
        #pragma unroll
        for (int st = 128; st > 0; st >>= 1) {
            if (tid < st) ired[tid] += ired[tid + st];
            __syncthreads();
        }
        npos = ired[0] >> 16;
        nneg = ired[0] & 0xFFFF;
    }

    // ---- per-row loss ----
    int i = blockIdx.x * 256 + tid;
    float w  = wP[0], b = bP[0];
    float wr = fmaxf(w, 0.f);

    int   t  = tgt[i];
    float rs = rowsum[i], sq = sqsum[i];
    float sj = s_h[t], nj = c_h[t];

    float nem = fmaxf(sqrtf(sq), EPS_COS);

    float dot = (sj * rs - sq) / nj;
    float nc  = sqrtf((float)E_ * sj * sj - 2.f * sj * rs + sq) / nj;
    float self_cos = dot / (nem * fmaxf(nc, EPS_COS));
    float self_sim = wr * self_cos + b;

    float A  = wr * rs / (nem * 16.0f);
    float xp =  A + b, xm = -A + b, xz = b;

    float ct = sj / nj;
    int np = npos, nm = nneg, nz = S_ - npos - nneg;
    if (fabsf(ct) * 16.0f >= EPS_COS) { if (ct > 0.f) np--; else nm--; }
    else nz--;

    float m = self_sim;
    if (np > 0) m = fmaxf(m, xp);
    if (nm > 0) m = fmaxf(m, xm);
    if (nz > 0) m = fmaxf(m, xz);
    float ssum = expf(self_sim - m)
               + (float)np * expf(xp - m)
               + (float)nm * expf(xm - m)
               + (float)nz * expf(xz - m);
    float contrib = m + logf(ssum) - self_sim;

    fred[tid] = contrib;
    __syncthreads();
    #pragma unroll
    for (int st = 128; st > 0; st >>= 1) {
        if (tid < st) fred[tid] += fred[tid + st];
        __syncthreads();
    }
    if (tid == 0) atomicAdd(outL, fred[0]);
}

extern "C" void kernel_launch(void* const* d_in, const int* in_sizes, int n_in,
                              void* d_out, int out_size, void* d_ws, size_t ws_size,
                              hipStream_t stream) {
    const float* inputs  = (const float*)d_in[0];
    const int*   targets = (const int*)d_in[1];
    const float* wP      = (const float*)d_in[2];
    const float* bP      = (const float*)d_in[3];
    float* outN = (float*)d_out;                    // [B,E] normalized
    float* outL = (float*)d_out + (size_t)B_ * E_;  // [1] loss

    float* wsf    = (float*)d_ws;
    float* rowsum = wsf;                     // B
    float* sqsum  = wsf + B_;                // B
    float* PBsum  = wsf + 2 * B_;            // 4096
    int*   PBtgt  = (int*)(PBsum + 4096);    // 4096

    rows_kernel<<<B_ / 8, 256, 0, stream>>>(inputs, targets, outN, outL,
                                            rowsum, sqsum, PBsum, PBtgt);
    loss_kernel<<<B_ / 256, 256, 0, stream>>>(rowsum, sqsum, targets,
                                              PBsum, PBtgt, wP, bP, outL);
}

// Round 12
// 19.746 us; speedup vs baseline: 1.3476x; 1.0476x over previous
//
#include <hip/hip_runtime.h>
#include <math.h>

#define B_ 32768
#define E_ 256
#define S_ 1024
#define EPS_COS 1e-8f
#define EPS_NORM 1e-12f

typedef float fx4 __attribute__((ext_vector_type(4)));

// ---------------- kernel 1: rows (oversubscribed, streamed) ----------------
// 2048 blocks x 256 threads, 16 rows/block: one row per 16-lane group.
// 4 fx4 loads/lane (64 B ILP), 4-level intra-16 butterfly (offsets <=8),
// NT stores. Per-block partial (sum over 16 rows, uniform target) -> PB[b].
__global__ __launch_bounds__(256) void rows_kernel(
        const float* __restrict__ x, const int* __restrict__ tgt,
        float* __restrict__ outN, float* __restrict__ outL,
        float* __restrict__ rowsum, float* __restrict__ sqsum,
        float* __restrict__ PBsum, int* __restrict__ PBtgt) {
    __shared__ float sSum[16];
    __shared__ int   sTgt[16];

    int tid = threadIdx.x;
    int g   = tid >> 4;                 // 16 groups of 16 lanes
    int li  = tid & 15;
    int row = blockIdx.x * 16 + g;

    if (blockIdx.x == 0 && tid == 0) outL[0] = 0.f;

    const fx4* __restrict__ xr = (const fx4*)(x + (size_t)row * E_);
    fx4* __restrict__ orow = (fx4*)(outN + (size_t)row * E_);

    fx4 a0 = xr[li];
    fx4 a1 = xr[li + 16];
    fx4 a2 = xr[li + 32];
    fx4 a3 = xr[li + 48];

    float sum = (a0.x + a0.y + a0.z + a0.w) + (a1.x + a1.y + a1.z + a1.w)
              + (a2.x + a2.y + a2.z + a2.w) + (a3.x + a3.y + a3.z + a3.w);
    float sq  = (a0.x*a0.x + a0.y*a0.y + a0.z*a0.z + a0.w*a0.w)
              + (a1.x*a1.x + a1.y*a1.y + a1.z*a1.z + a1.w*a1.w)
              + (a2.x*a2.x + a2.y*a2.y + a2.z*a2.z + a2.w*a2.w)
              + (a3.x*a3.x + a3.y*a3.y + a3.z*a3.z + a3.w*a3.w);

    #pragma unroll
    for (int o = 8; o >= 1; o >>= 1) {  // intra-16-lane only
        sum += __shfl_xor(sum, o, 64);
        sq  += __shfl_xor(sq,  o, 64);
    }

    float rn = 1.0f / fmaxf(sqrtf(sq), EPS_NORM);
    __builtin_nontemporal_store(a0 * rn, &orow[li]);
    __builtin_nontemporal_store(a1 * rn, &orow[li + 16]);
    __builtin_nontemporal_store(a2 * rn, &orow[li + 32]);
    __builtin_nontemporal_store(a3 * rn, &orow[li + 48]);

    if (li == 0) {
        rowsum[row] = sum;
        sqsum[row]  = sq;
        sSum[g] = sum;
        sTgt[g] = tgt[row];
    }
    __syncthreads();
    if (tid == 0) {
        float tot = 0.f;
        int t0 = sTgt[0];
        int same = 1;
        #pragma unroll
        for (int k = 0; k < 16; ++k) {
            tot += sSum[k];
            same &= (sTgt[k] == t0);
        }
        PBsum[blockIdx.x] = tot;
        PBtgt[blockIdx.x] = same ? t0 : -1;
    }
}

// ---------------- kernel 2: loss -------------------------------------------
// 128 blocks x 256 threads; block handles rows [256b, 256b+256).
// Fast path: PBtgt[i]==i>>1 for all i  =>  s[k]=PBsum[2k]+PBsum[2k+1], n=32.
// Slow path: rebuild full histogram from rowsum/tgt with LDS atomics.
__global__ __launch_bounds__(256) void loss_kernel(
        const float* __restrict__ rowsum, const float* __restrict__ sqsum,
        const int* __restrict__ tgt,
        const float* __restrict__ PBsum, const int* __restrict__ PBtgt,
        const float* __restrict__ wP, const float* __restrict__ bP,
        float* __restrict__ outL) {
    __shared__ float s_h[S_];
    __shared__ float c_h[S_];
    __shared__ int   ired[256];
    __shared__ float fred[256];

    int tid = threadIdx.x;

    // build s_h from PB (4 speakers per thread) + fast-path check + buckets
    int packed = 0;     // (npos<<16) | nneg
    int bad = 0;
    #pragma unroll
    for (int j = 0; j < 4; ++j) {
        int k = tid * 4 + j;
        float sk = PBsum[2*k] + PBsum[2*k+1];
        int ok = (PBtgt[2*k] == k) & (PBtgt[2*k+1] == k);
        bad |= !ok;
        s_h[k] = sk;
        c_h[k] = 32.0f;
        float cv = sk * (1.0f / 32.0f);
        if (fabsf(cv) * 16.0f >= EPS_COS) packed += (cv > 0.f) ? (1 << 16) : 1;
    }
    ired[tid] = packed | (bad ? (1 << 15) : 0);   // bit15 = bad flag
    __syncthreads();
    #pragma unroll
    for (int st = 128; st > 0; st >>= 1) {
        if (tid < st) {
            int a = ired[tid], b = ired[tid + st];
            ired[tid] = ((a + b) & ~(1 << 15)) | ((a | b) & (1 << 15));
        }
        __syncthreads();
    }
    int agg  = ired[0];
    int slow = (agg >> 15) & 1;
    int npos = (agg >> 16) & 0xFFFF;
    int nneg = agg & 0x7FFF;

    if (slow) {   // ---- general path: rebuild histogram from rows ----
        __syncthreads();
        s_h[tid] = 0.f; s_h[tid + 256] = 0.f; s_h[tid + 512] = 0.f; s_h[tid + 768] = 0.f;
        c_h[tid] = 0.f; c_h[tid + 256] = 0.f; c_h[tid + 512] = 0.f; c_h[tid + 768] = 0.f;
        __syncthreads();
        for (int i = tid; i < B_; i += 256) {
            int t = tgt[i];
            atomicAdd(&s_h[t], rowsum[i]);
            atomicAdd(&c_h[t], 1.0f);
        }
        __syncthreads();
        packed = 0;
        #pragma unroll
        for (int j = 0; j < 4; ++j) {
            int k = tid * 4 + j;
            float cv = s_h[k] / c_h[k];
            if (fabsf(cv) * 16.0f >= EPS_COS) packed += (cv > 0.f) ? (1 << 16) : 1;
        }
        ired[tid] = packed;
        __syncthreads();
        #pragma unroll
        for (int st = 128; st > 0; st >>= 1) {
            if (tid < st) ired[tid] += ired[tid + st];
            __syncthreads();
        }
        npos = ired[0] >> 16;
        nneg = ired[0] & 0xFFFF;
    }

    // ---- per-row loss ----
    int i = blockIdx.x * 256 + tid;
    float w  = wP[0], b = bP[0];
    float wr = fmaxf(w, 0.f);

    int   t  = tgt[i];
    float rs = rowsum[i], sq = sqsum[i];
    float sj = s_h[t], nj = c_h[t];

    float nem = fmaxf(sqrtf(sq), EPS_COS);

    float dot = (sj * rs - sq) / nj;
    float nc  = sqrtf((float)E_ * sj * sj - 2.f * sj * rs + sq) / nj;
    float self_cos = dot / (nem * fmaxf(nc, EPS_COS));
    float self_sim = wr * self_cos + b;

    float A  = wr * rs / (nem * 16.0f);
    float xp =  A + b, xm = -A + b, xz = b;

    float ct = sj / nj;
    int np = npos, nm = nneg, nz = S_ - npos - nneg;
    if (fabsf(ct) * 16.0f >= EPS_COS) { if (ct > 0.f) np--; else nm--; }
    else nz--;

    float m = self_sim;
    if (np > 0) m = fmaxf(m, xp);
    if (nm > 0) m = fmaxf(m, xm);
    if (nz > 0) m = fmaxf(m, xz);
    float ssum = expf(self_sim - m)
               + (float)np * expf(xp - m)
               + (float)nm * expf(xm - m)
               + (float)nz * expf(xz - m);
    float contrib = m + logf(ssum) - self_sim;

    fred[tid] = contrib;
    __syncthreads();
    #pragma unroll
    for (int st = 128; st > 0; st >>= 1) {
        if (tid < st) fred[tid] += fred[tid + st];
        __syncthreads();
    }
    if (tid == 0) atomicAdd(outL, fred[0]);
}

extern "C" void kernel_launch(void* const* d_in, const int* in_sizes, int n_in,
                              void* d_out, int out_size, void* d_ws, size_t ws_size,
                              hipStream_t stream) {
    const float* inputs  = (const float*)d_in[0];
    const int*   targets = (const int*)d_in[1];
    const float* wP      = (const float*)d_in[2];
    const float* bP      = (const float*)d_in[3];
    float* outN = (float*)d_out;                    // [B,E] normalized
    float* outL = (float*)d_out + (size_t)B_ * E_;  // [1] loss

    float* wsf    = (float*)d_ws;
    float* rowsum = wsf;                     // B
    float* sqsum  = wsf + B_;                // B
    float* PBsum  = wsf + 2 * B_;            // 2048
    int*   PBtgt  = (int*)(PBsum + 2048);    // 2048

    rows_kernel<<<B_ / 16, 256, 0, stream>>>(inputs, targets, outN, outL,
                                             rowsum, sqsum, PBsum, PBtgt);
    loss_kernel<<<B_ / 256, 256, 0, stream>>>(rowsum, sqsum, targets,
                                              PBsum, PBtgt, wP, bP, outL);
}